// Round 17
// baseline (182.093 us; speedup 1.0000x reference)
//
#include <hip/hip_runtime.h>
#include <cstdint>
#include <cstddef>

#define KTOT 25088   // C*P*P = 512*49 (K-permuted: k' = bin*512 + c); row BYTES in fp8
#define NBOX 2048
#define HID  1024

typedef __bf16 bf16x8 __attribute__((ext_vector_type(8)));
typedef float  f32x4  __attribute__((ext_vector_type(4)));

__device__ __forceinline__ unsigned short f2bf(float f) {
  union { float f; unsigned u; } v; v.f = f;
  unsigned r = v.u + 0x7FFFu + ((v.u >> 16) & 1u);   // RNE
  return (unsigned short)(r >> 16);
}

// float -> OCP e4m3fn, RNE, saturating to 448, subnormal-correct.
__device__ __forceinline__ unsigned char f2fp8(float x) {
  union { float f; unsigned u; } v; v.f = x;
  unsigned sign = (v.u >> 31) << 7;
  float a = fabsf(x);
  if (!(a >= 0.001953125f)) {
    int q = (int)rintf(a * 512.f);
    return (unsigned char)(sign | q);
  }
  if (a >= 464.f) return (unsigned char)(sign | 0x7E);
  int e = (int)((v.u >> 23) & 0xFF) - 127;
  if (e < -6) {
    int q = (int)rintf(ldexpf(a, 9));
    return (unsigned char)(sign | q);
  }
  int q = (int)rintf(ldexpf(a, 3 - e));
  if (q == 16) { e += 1; q = 8; }
  if (e > 8) return (unsigned char)(sign | 0x7E);
  return (unsigned char)(sign | ((e + 7) << 3) | (q - 8));
}

__device__ __forceinline__ float scalar_f(const void* p) {
  int iv = *(const int*)p;
  if (iv > 0 && iv < (1 << 20)) return (float)iv;
  return *(const float*)p;
}

// ---- k_pre1: W1->fp8 transpose [0,6272) + temporal mean [6272,7840) + IoU [7840,7848)
__global__ __launch_bounds__(256) void k_pre1(
    const float* __restrict__ W1, unsigned char* __restrict__ W1T,
    const float* __restrict__ feature, float* __restrict__ fbhwc,
    const float* __restrict__ prop, const float* __restrict__ gtb,
    float* __restrict__ max_iou, int* __restrict__ assign,
    int* __restrict__ flag) {
  __shared__ unsigned char tile[64][68];
  int blk = blockIdx.x;
  int t = threadIdx.x;
  if (blk < 6272) {
    int kp0 = (blk % 392) * 64;
    int h0  = (blk / 392) * 64;
    int seg = t & 15, ro = t >> 4;
#pragma unroll
    for (int r = 0; r < 4; ++r) {
      int i = ro + r * 16;
      int kp = kp0 + i;
      int srow = (kp & 511) * 49 + (kp >> 9);
      float4 v = *(const float4*)(W1 + (size_t)srow * 1024 + h0 + seg * 4);
      tile[i][seg*4+0] = f2fp8(v.x * 64.f);
      tile[i][seg*4+1] = f2fp8(v.y * 64.f);
      tile[i][seg*4+2] = f2fp8(v.z * 64.f);
      tile[i][seg*4+3] = f2fp8(v.w * 64.f);
    }
    __syncthreads();
#pragma unroll
    for (int r = 0; r < 4; ++r) {
      int hi = ro + r * 16;
      unsigned a = tile[seg*4+0][hi];
      unsigned b = tile[seg*4+1][hi];
      unsigned c = tile[seg*4+2][hi];
      unsigned d = tile[seg*4+3][hi];
      *(unsigned*)(W1T + (size_t)(h0+hi)*KTOT + kp0 + seg*4) =
          a | (b << 8) | (c << 16) | (d << 24);
    }
  } else if (blk < 7840) {
    int id = (blk - 6272) * 256 + t;
    if (id >= 4 * 512 * 196) return;
    int pix = id % 196;
    int c   = (id / 196) & 511;
    int b   = id / (196 * 512);
    const float* p = feature + ((size_t)(b * 512 + c) * 8) * 196 + pix;
    float s = 0.f;
#pragma unroll
    for (int tt = 0; tt < 8; ++tt) s += p[tt * 196];
    fbhwc[((size_t)(b * 196 + pix)) * 512 + c] = s * 0.125f;
  } else {
    float* g = (float*)tile;
    int gid = (blk - 7840) * 256 + t;
    int b = gid >> 9;
    if (t < 128) g[t] = gtb[b * 128 + t];
    __syncthreads();
    float x1 = prop[gid * 4 + 0], y1 = prop[gid * 4 + 1];
    float x2 = prop[gid * 4 + 2], y2 = prop[gid * 4 + 3];
    float aa = (x2 - x1) * (y2 - y1);
    float best = -1e30f; int arg = 0;
    for (int m = 0; m < 32; ++m) {
      float gx1 = g[m*4], gy1 = g[m*4+1], gx2 = g[m*4+2], gy2 = g[m*4+3];
      float iw = fmaxf(fminf(x2, gx2) - fmaxf(x1, gx1), 0.f);
      float ih = fmaxf(fminf(y2, gy2) - fmaxf(y1, gy1), 0.f);
      float inter = iw * ih;
      float ab = (gx2 - gx1) * (gy2 - gy1);
      float iou = inter / (aa + ab - inter + 1e-8f);
      if (iou > best) { best = iou; arg = m; }
    }
    max_iou[gid] = best; assign[gid] = arg;
    if (best >= 0.85f) atomicOr(flag, 1);
  }
}

// ---- k_pre2: ROI-pool -> fp8 Apool, 4 blocks/box (bins 0-11/12-23/24-35/36-48)
__global__ __launch_bounds__(256) void k_pre2(
    const float* __restrict__ fbhwc, const float* __restrict__ prop,
    const void* ihp, const void* iwp, unsigned char* __restrict__ Apool) {
  int blk = blockIdx.x;
  int t = threadIdx.x;
  int n = blk >> 2;
  int q = blk & 3;
  int start = q * 12;
  int end   = (q == 3) ? 49 : start + 12;
  float sy = 14.f / scalar_f(ihp);
  float sx = 14.f / scalar_f(iwp);
  float bx1 = prop[n*4+0]*sx, by1 = prop[n*4+1]*sy;
  float bx2 = prop[n*4+2]*sx, by2 = prop[n*4+3]*sy;
  const float* fb = fbhwc + (size_t)(n >> 9) * 196 * 512;
  unsigned char* arow = Apool + (size_t)n * KTOT;
  int c4 = (t & 127) << 2;
  int bh = t >> 7;
  for (int b2i = start; b2i < end; b2i += 2) {
    int bin = b2i + bh;
    if (bin >= end) continue;
    int py = bin / 7, px = bin - py * 7;
    float y = by1 + ((py + 0.5f) * (1.f/7.f)) * (by2 - by1) - 0.5f;
    float x = bx1 + ((px + 0.5f) * (1.f/7.f)) * (bx2 - bx1) - 0.5f;
    float y0f = floorf(y), x0f = floorf(x);
    float wy = y - y0f, wx = x - x0f;
    int y0  = min(max((int)y0f, 0), 13);
    int y1i = min(max((int)y0f + 1, 0), 13);
    int x0  = min(max((int)x0f, 0), 13);
    int x1i = min(max((int)x0f + 1, 0), 13);
    float w00 = (1.f - wy) * (1.f - wx), w01 = (1.f - wy) * wx;
    float w10 = wy * (1.f - wx),         w11 = wy * wx;
    const float4 f00 = *(const float4*)(fb + (y0 * 14 + x0 ) * 512 + c4);
    const float4 f01 = *(const float4*)(fb + (y0 * 14 + x1i) * 512 + c4);
    const float4 f10 = *(const float4*)(fb + (y1i * 14 + x0 ) * 512 + c4);
    const float4 f11 = *(const float4*)(fb + (y1i * 14 + x1i) * 512 + c4);
    float vx = f00.x*w00 + f01.x*w01 + f10.x*w10 + f11.x*w11;
    float vy = f00.y*w00 + f01.y*w01 + f10.y*w10 + f11.y*w11;
    float vz = f00.z*w00 + f01.z*w01 + f10.z*w10 + f11.z*w11;
    float vw = f00.w*w00 + f01.w*w01 + f10.w*w10 + f11.w*w11;
    unsigned pk = (unsigned)f2fp8(vx) | ((unsigned)f2fp8(vy) << 8)
                | ((unsigned)f2fp8(vz) << 16) | ((unsigned)f2fp8(vw) << 24);
    *(unsigned*)(arow + bin * 512 + c4) = pk;
  }
}

__device__ __forceinline__ void gload16(const unsigned char* g, unsigned char* l) {
  __builtin_amdgcn_global_load_lds(
      (const __attribute__((address_space(1))) unsigned int*)g,
      (__attribute__((address_space(3))) unsigned int*)l, 16, 0, 0);
}

// ---- GEMM1 fp8: 256x256 tile, BK=64, ring-4 with LEAD-3 staging (vmcnt(8));
//      rolling in-place register refill; NO setprio (m190: hurts lockstep GEMM).
//      Grid = 8(M) x 4(N) x 8(splitK) = 256 blocks = 1/CU. 128KB dynamic LDS.
__global__ __launch_bounds__(512, 2) void k_gemm1(
    const unsigned char* __restrict__ A,   // 2048 x 25088 fp8
    const unsigned char* __restrict__ B,   // 1024 x 25088 fp8
    unsigned short* __restrict__ hp)       // 8 x 2048 x 1024 bf16 partials (x64 scale)
{
  extern __shared__ unsigned char lds[];   // 4 slots x 32768 B: [A 16K | B 16K]
  const int tid  = threadIdx.x;
  const int w    = tid >> 6;
  const int lane = tid & 63;
  const int l15  = lane & 15;
  const int wr = w >> 2, wc = w & 3;
  const int bid = (int)blockIdx.x;
  const int wg  = (bid & 7) * 32 + (bid >> 3);
  const int kb  = wg >> 5;
  const int gy  = (wg >> 2) & 7;
  const int gx  = wg & 3;

  f32x4 acc[8][4];
  const f32x4 zero = {0.f, 0.f, 0.f, 0.f};
#pragma unroll
  for (int m = 0; m < 8; ++m)
#pragma unroll
    for (int n = 0; n < 4; ++n) acc[m][n] = zero;

  const int xsw  = (tid & 7) ^ ((tid >> 3) & 7);
  const int rloc = ((tid >> 3) << 1) + (xsw >> 2);
  const int qsrc = xsw & 3;
  const size_t kbase = (size_t)kb * 3136;
  const unsigned char* gAp = A + (size_t)(gy * 256 + rloc) * KTOT + kbase + qsrc * 16;
  const unsigned char* gBp = B + (size_t)(gx * 256 + rloc) * KTOT + kbase + qsrc * 16;
  const int dstc = tid * 16;

  const int g4   = lane >> 4;
  const int qb   = g4 >> 1;
  const int h8   = (g4 & 1) * 8;
  const int rpar = (l15 & 1) << 2;
  const int lin  = l15 >> 1;
  const int P0 = ((qb)     | rpar) ^ lin;
  const int P1 = ((qb + 2) | rpar) ^ lin;
  const int aoff0 = wr * 8192 + lin * 128 + P0 * 16 + h8;
  const int aoff1 = wr * 8192 + lin * 128 + P1 * 16 + h8;
  const int boff0 = 16384 + wc * 4096 + lin * 128 + P0 * 16 + h8;
  const int boff1 = 16384 + wc * 4096 + lin * 128 + P1 * 16 + h8;

  long A0[8], A1[8], Bk0[4], Bk1[4];

#define STG(SLOT, KN) { \
    gload16(gAp + (KN),                      lds + (SLOT)*32768 + dstc); \
    gload16(gAp + (KN) + (size_t)128 * KTOT, lds + (SLOT)*32768 + 8192 + dstc); \
    gload16(gBp + (KN),                      lds + (SLOT)*32768 + 16384 + dstc); \
    gload16(gBp + (KN) + (size_t)128 * KTOT, lds + (SLOT)*32768 + 24576 + dstc); }
#define LDA(m, SLOT) { \
    A0[m] = *(const long*)(lds + (SLOT)*32768 + aoff0 + (m)*1024); \
    A1[m] = *(const long*)(lds + (SLOT)*32768 + aoff1 + (m)*1024); }
#define LDB(n, SLOT) { \
    Bk0[n] = *(const long*)(lds + (SLOT)*32768 + boff0 + (n)*1024); \
    Bk1[n] = *(const long*)(lds + (SLOT)*32768 + boff1 + (n)*1024); }
#define VM8 asm volatile("s_waitcnt vmcnt(8)" ::: "memory");
#define VM4 asm volatile("s_waitcnt vmcnt(4)" ::: "memory");
#define VM0 asm volatile("s_waitcnt vmcnt(0)" ::: "memory");
#define VMN

  // STEP: regs hold step-s frags (slot CS). Stage slot CS+3 (lead-3);
  // refill regs from slot CS+1 rolling in-place inside the MFMA cluster.
#define STEP(CS, DOSTG, KN, VMASM, DOREFILL)                                   \
  {                                                                            \
    if (DOSTG) STG((((CS)+3)&3), KN)                                           \
    VMASM                                                                      \
    __builtin_amdgcn_s_barrier();                                              \
    _Pragma("unroll") for (int m = 0; m < 8; ++m) {                            \
      _Pragma("unroll") for (int n = 0; n < 4; ++n) {                          \
        acc[m][n] = __builtin_amdgcn_mfma_f32_16x16x32_fp8_fp8(                \
            A0[m], Bk0[n], acc[m][n], 0, 0, 0);                                \
        acc[m][n] = __builtin_amdgcn_mfma_f32_16x16x32_fp8_fp8(                \
            A1[m], Bk1[n], acc[m][n], 0, 0, 0);                                \
      }                                                                        \
      if (DOREFILL) LDA(m, (((CS)+1)&3))                                       \
    }                                                                          \
    if (DOREFILL) { _Pragma("unroll") for (int n = 0; n < 4; ++n)              \
                      LDB(n, (((CS)+1)&3)) }                                   \
  }

  // prologue: stage slots 0,1,2 (k=0,64,128); vmcnt(8) -> slot0 landed.
  STG(0, 0)
  STG(1, 64)
  STG(2, 128)
  VM8
  __builtin_amdgcn_s_barrier();
#pragma unroll
  for (int m = 0; m < 8; ++m) LDA(m, 0)
#pragma unroll
  for (int n = 0; n < 4; ++n) LDB(n, 0)

  // main: 49 steps. s=0..43 quads (stage s+3 <= 46); 44,45 stage 47,48;
  // 46 drains to vmcnt(4) (slot47 landed); 47 drains 0 (slot48); 48 computes.
#pragma unroll 1
  for (int s4 = 0; s4 < 44; s4 += 4) {
    STEP(0, true, (size_t)(s4 + 3) * 64, VM8, true)
    STEP(1, true, (size_t)(s4 + 4) * 64, VM8, true)
    STEP(2, true, (size_t)(s4 + 5) * 64, VM8, true)
    STEP(3, true, (size_t)(s4 + 6) * 64, VM8, true)
  }
  STEP(0, true, (size_t)47 * 64, VM8, true)   // s=44
  STEP(1, true, (size_t)48 * 64, VM8, true)   // s=45
  STEP(2, false, 0, VM4, true)                // s=46 (47 landed)
  STEP(3, false, 0, VM0, true)                // s=47 (48 landed)
  STEP(0, false, 0, VMN, false)               // s=48

#undef STEP
#undef VMN
#undef VM0
#undef VM4
#undef VM8
#undef LDB
#undef LDA
#undef STG

  unsigned short* o = hp + (size_t)kb * (2048u * 1024u);
  const int r0 = gy * 256 + wr * 128 + ((lane >> 4) << 2);
  const int c0 = gx * 256 + wc * 64 + l15;
#pragma unroll
  for (int m = 0; m < 8; ++m)
#pragma unroll
    for (int n = 0; n < 4; ++n)
#pragma unroll
      for (int j = 0; j < 4; ++j)
        o[(size_t)(r0 + m * 16 + j) * 1024 + c0 + n * 16] = f2bf(acc[m][n][j]);
}

// ---- GEMM template (GEMM2 only, bf16): 128x128 tile, 2-phase dbuf
__device__ __forceinline__ void gload16s(const unsigned short* g, unsigned short* l) {
  __builtin_amdgcn_global_load_lds(
      (const __attribute__((address_space(1))) unsigned int*)g,
      (__attribute__((address_space(3))) unsigned int*)l, 16, 0, 0);
}

template<int OUTBF>
__global__ __launch_bounds__(256, 4) void k_gemm(
    const unsigned short* __restrict__ A,
    const unsigned short* __restrict__ B,
    void* __restrict__ outp,
    int Kst, int kIters, int nTileBits, int mTileBits, int ldc)
{
  __shared__ unsigned short As[2][4096];
  __shared__ unsigned short Bs[2][4096];
  const int tid  = threadIdx.x;
  const int w    = tid >> 6;
  const int lane = tid & 63;
  const int nwg = (int)gridDim.x, cpx = nwg >> 3;
  const int bid = (int)blockIdx.x;
  const int wg  = (bid & 7) * cpx + (bid >> 3);
  const int kb  = wg >> (mTileBits + nTileBits);
  const int rem = wg & ((1 << (mTileBits + nTileBits)) - 1);
  const int gy  = rem >> nTileBits;
  const int gx  = rem & ((1 << nTileBits) - 1);
  const int wr = w >> 1, wc = w & 1;

  f32x4 acc[4][4];
  const f32x4 zero = {0.f, 0.f, 0.f, 0.f};
#pragma unroll
  for (int m = 0; m < 4; ++m)
#pragma unroll
    for (int n = 0; n < 4; ++n) acc[m][n] = zero;

  const int r0   = 32 * w + (lane >> 2);
  const int qsrc = (lane & 3) ^ ((lane >> 3) & 3);
  const size_t kbase = (size_t)kb * kIters * 32;
  const unsigned short* gA = A + (size_t)(gy * 128 + r0) * Kst + kbase + qsrc * 8;
  const unsigned short* gB = B + (size_t)(gx * 128 + r0) * Kst + kbase + qsrc * 8;
  const int ldst = r0 * 32 + (lane & 3) * 8;

  const int swq = ((lane >> 4) ^ ((lane >> 1) & 3)) * 8;
  const int ar = (wr * 64 + (lane & 15)) * 32 + swq;
  const int br = (wc * 64 + (lane & 15)) * 32 + swq;

#define STAGE(bufi, it) do {                                         \
    const unsigned short* pa = gA + (size_t)(it) * 32;               \
    const unsigned short* pb = gB + (size_t)(it) * 32;               \
    gload16s(pa,                      &As[bufi][ldst]);              \
    gload16s(pa + (size_t)16 * Kst,   &As[bufi][ldst + 512]);        \
    gload16s(pb,                      &Bs[bufi][ldst]);              \
    gload16s(pb + (size_t)16 * Kst,   &Bs[bufi][ldst + 512]);        \
  } while (0)

  STAGE(0, 0);
  int cur = 0;
  for (int kk = 0; kk < kIters; ++kk) {
    __syncthreads();
    if (kk + 1 < kIters) STAGE(cur ^ 1, kk + 1);
    bf16x8 af[4], bfr[4];
#pragma unroll
    for (int m = 0; m < 4; ++m)
      af[m] = *reinterpret_cast<const bf16x8*>(&As[cur][ar + m * 512]);
#pragma unroll
    for (int n = 0; n < 4; ++n)
      bfr[n] = *reinterpret_cast<const bf16x8*>(&Bs[cur][br + n * 512]);
#pragma unroll
    for (int m = 0; m < 4; ++m)
#pragma unroll
      for (int n = 0; n < 4; ++n)
        acc[m][n] = __builtin_amdgcn_mfma_f32_16x16x32_bf16(af[m], bfr[n], acc[m][n], 0, 0, 0);
    cur ^= 1;
  }
#undef STAGE

  const size_t M = (size_t)(1 << mTileBits) * 128;
  const size_t splitStride = M * (size_t)ldc;
  const int r0o = gy * 128 + wr * 64 + ((lane >> 4) << 2);
  const int c0o = gx * 128 + wc * 64 + (lane & 15);
  if (OUTBF) {
    unsigned short* o = (unsigned short*)outp + (size_t)kb * splitStride;
#pragma unroll
    for (int m = 0; m < 4; ++m)
#pragma unroll
      for (int n = 0; n < 4; ++n)
#pragma unroll
        for (int j = 0; j < 4; ++j)
          o[(size_t)(r0o + m * 16 + j) * ldc + c0o + n * 16] = f2bf(acc[m][n][j]);
  } else {
    float* o = (float*)outp + (size_t)kb * splitStride;
#pragma unroll
    for (int m = 0; m < 4; ++m)
#pragma unroll
      for (int n = 0; n < 4; ++n)
#pragma unroll
        for (int j = 0; j < 4; ++j)
          o[(size_t)(r0o + m * 16 + j) * ldc + c0o + n * 16] = acc[m][n][j];
  }
}

// ---- combine (x 1/64 un-scale) + bias + ReLU -> hidden bf16; + W2 transpose
__global__ __launch_bounds__(256) void k_combine(const unsigned short* __restrict__ hp,
                                                 const float* __restrict__ b1,
                                                 unsigned short* __restrict__ hidden,
                                                 const float* __restrict__ W2,
                                                 unsigned short* __restrict__ W2T) {
  int blk = blockIdx.x;
  if (blk >= 1024) {
    int id = (blk - 1024) * 256 + threadIdx.x;
    int cls = id >> 10, k = id & 1023;
    float v = (cls < 80) ? W2[(size_t)k * 80 + cls] : 0.f;
    W2T[id] = f2bf(v);
    return;
  }
  int gid = blk * 256 + threadIdx.x;
  int id8 = gid * 8;
  int h = id8 & 1023;
  float a[8] = {0.f, 0.f, 0.f, 0.f, 0.f, 0.f, 0.f, 0.f};
#pragma unroll
  for (int s = 0; s < 8; ++s) {
    uint4 u = *(const uint4*)(hp + (size_t)s * 2097152 + id8);
    unsigned uu[4] = {u.x, u.y, u.z, u.w};
#pragma unroll
    for (int q = 0; q < 4; ++q) {
      union { unsigned u; float f; } lo, hi;
      lo.u = uu[q] << 16; hi.u = uu[q] & 0xFFFF0000u;
      a[2*q]   += lo.f;
      a[2*q+1] += hi.f;
    }
  }
  unsigned out[4];
#pragma unroll
  for (int q = 0; q < 4; ++q) {
    float v0 = a[2*q]   * 0.015625f + b1[h + 2*q];
    float v1 = a[2*q+1] * 0.015625f + b1[h + 2*q + 1];
    unsigned l  = f2bf(fmaxf(v0, 0.f));
    unsigned hh = f2bf(fmaxf(v1, 0.f));
    out[q] = l | (hh << 16);
  }
  *(uint4*)(hidden + id8) = make_uint4(out[0], out[1], out[2], out[3]);
}

// ---- BCE from gemm2 split-K partials (8 x 2048 x 128 f32)
__global__ __launch_bounds__(256) void k_bce(const float* __restrict__ hp2,
                                             const float* __restrict__ b2,
                                             const float* __restrict__ gtc,
                                             const int* __restrict__ assign,
                                             float* __restrict__ per) {
  __shared__ float red[256];
  int t = threadIdx.x;
  int box = t >> 4, li = t & 15;
  int n = blockIdx.x * 16 + box;
  int lab = ((n >> 9) * 32 + assign[n]) * 80;
  float s = 0.f;
#pragma unroll
  for (int j = 0; j < 5; ++j) {
    int c = li + 16 * j;
    size_t o = (size_t)n * 128 + c;
    float x = b2[c];
#pragma unroll
    for (int sp = 0; sp < 8; ++sp) x += hp2[o + (size_t)sp * 262144];
    float y = gtc[lab + c];
    float ce = log1pf(expf(-fabsf(x)));
    s += y * (fmaxf(-x, 0.f) + ce) + (1.f - y) * (fmaxf(x, 0.f) + ce);
  }
  red[t] = s;
  __syncthreads();
  if (li == 0) {
    float tot = 0.f;
#pragma unroll
    for (int i = 0; i < 16; ++i) tot += red[box * 16 + i];
    per[n] = tot * (1.f / 80.f);
  }
}

// ---- fg-masked per-batch mean
__global__ __launch_bounds__(512) void k_reduce(const float* __restrict__ per,
                                                const float* __restrict__ max_iou,
                                                const int* __restrict__ flag,
                                                float* __restrict__ out) {
  __shared__ float sv[8], sf[8];
  int b = blockIdx.x, tid = threadIdx.x;
  float thr = (*flag) ? 0.85f : 0.5f;
  int n = b * 512 + tid;
  float f = (max_iou[n] >= thr) ? 1.f : 0.f;
  float v = per[n] * f;
#pragma unroll
  for (int o = 32; o > 0; o >>= 1) {
    v += __shfl_down(v, o);
    f += __shfl_down(f, o);
  }
  int wv = tid >> 6;
  if ((tid & 63) == 0) { sv[wv] = v; sf[wv] = f; }
  __syncthreads();
  if (tid == 0) {
    float S = 0.f, F = 0.f;
#pragma unroll
    for (int i = 0; i < 8; ++i) { S += sv[i]; F += sf[i]; }
    out[b] = (F > 0.f) ? S / fmaxf(F, 1.f) : 0.f;
  }
}

extern "C" void kernel_launch(void* const* d_in, const int* in_sizes, int n_in,
                              void* d_out, int out_size, void* d_ws, size_t ws_size,
                              hipStream_t stream) {
  const float* feature = (const float*)d_in[0];
  const float* prop    = (const float*)d_in[1];
  const float* gtb     = (const float*)d_in[2];
  const float* gtc     = (const float*)d_in[3];
  const float* W1      = (const float*)d_in[4];
  const float* b1      = (const float*)d_in[5];
  const float* W2      = (const float*)d_in[6];
  const float* b2      = (const float*)d_in[7];
  const void*  ihp     = d_in[8];
  const void*  iwp     = d_in[9];

  char* ws = (char*)d_ws;
  float*          fbhwc  = (float*)(ws);
  unsigned char*  W1T    = (unsigned char*)(ws + 1605632);
  unsigned char*  Apool  = (unsigned char*)(ws + 52985856);
  unsigned short* hp     = (unsigned short*)(ws + 155746304);
  float*          max_iou= (float*)(ws + 189300736);
  int*            assign = (int*)(ws + 189308928);
  float*          per    = (float*)(ws + 189317120);
  int*            flag   = (int*)(ws + 189325312);
  unsigned short* hidden = (unsigned short*)W1T;
  unsigned short* W2T    = (unsigned short*)Apool;
  float*          hp2    = (float*)((char*)Apool + 262144);

  hipFuncSetAttribute((const void*)k_gemm1,
                      hipFuncAttributeMaxDynamicSharedMemorySize, 131072);

  hipMemsetAsync(flag, 0, sizeof(int), stream);
  k_pre1   <<<7848, 256, 0, stream>>>(W1, W1T, feature, fbhwc, prop, gtb,
                                      max_iou, assign, flag);
  k_pre2   <<<8192, 256, 0, stream>>>(fbhwc, prop, ihp, iwp, Apool);
  k_gemm1  <<<256, 512, 131072, stream>>>(Apool, W1T, hp);
  k_combine<<<1536, 256, 0, stream>>>(hp, b1, hidden, W2, W2T);
  k_gemm<0><<<128, 256, 0, stream>>>(hidden, W2T, hp2, 1024, 4, 0, 4, 128);
  k_bce    <<<128, 256, 0, stream>>>(hp2, b2, gtc, assign, per);
  k_reduce <<<4, 512, 0, stream>>>(per, max_iou, flag, (float*)d_out);
}

// Round 18
// 178.957 us; speedup vs baseline: 1.0175x; 1.0175x over previous
//
#include <hip/hip_runtime.h>
#include <cstdint>
#include <cstddef>

#define KTOT 25088   // C*P*P = 512*49 (K-permuted: k' = bin*512 + c); row BYTES in fp8
#define NBOX 2048
#define HID  1024

typedef __bf16 bf16x8 __attribute__((ext_vector_type(8)));
typedef float  f32x4  __attribute__((ext_vector_type(4)));

__device__ __forceinline__ unsigned short f2bf(float f) {
  union { float f; unsigned u; } v; v.f = f;
  unsigned r = v.u + 0x7FFFu + ((v.u >> 16) & 1u);   // RNE
  return (unsigned short)(r >> 16);
}

// float -> OCP e4m3fn, RNE, saturating to 448, subnormal-correct.
__device__ __forceinline__ unsigned char f2fp8(float x) {
  union { float f; unsigned u; } v; v.f = x;
  unsigned sign = (v.u >> 31) << 7;
  float a = fabsf(x);
  if (!(a >= 0.001953125f)) {
    int q = (int)rintf(a * 512.f);
    return (unsigned char)(sign | q);
  }
  if (a >= 464.f) return (unsigned char)(sign | 0x7E);
  int e = (int)((v.u >> 23) & 0xFF) - 127;
  if (e < -6) {
    int q = (int)rintf(ldexpf(a, 9));
    return (unsigned char)(sign | q);
  }
  int q = (int)rintf(ldexpf(a, 3 - e));
  if (q == 16) { e += 1; q = 8; }
  if (e > 8) return (unsigned char)(sign | 0x7E);
  return (unsigned char)(sign | ((e + 7) << 3) | (q - 8));
}

__device__ __forceinline__ float scalar_f(const void* p) {
  int iv = *(const int*)p;
  if (iv > 0 && iv < (1 << 20)) return (float)iv;
  return *(const float*)p;
}

// ---- k_pre1: W1->fp8 transpose [0,6272) + temporal mean [6272,7840) + IoU [7840,7848)
__global__ __launch_bounds__(256) void k_pre1(
    const float* __restrict__ W1, unsigned char* __restrict__ W1T,
    const float* __restrict__ feature, float* __restrict__ fbhwc,
    const float* __restrict__ prop, const float* __restrict__ gtb,
    float* __restrict__ max_iou, int* __restrict__ assign,
    int* __restrict__ flag) {
  __shared__ unsigned char tile[64][68];
  int blk = blockIdx.x;
  int t = threadIdx.x;
  if (blk < 6272) {
    int kp0 = (blk % 392) * 64;
    int h0  = (blk / 392) * 64;
    int seg = t & 15, ro = t >> 4;
#pragma unroll
    for (int r = 0; r < 4; ++r) {
      int i = ro + r * 16;
      int kp = kp0 + i;
      int srow = (kp & 511) * 49 + (kp >> 9);
      float4 v = *(const float4*)(W1 + (size_t)srow * 1024 + h0 + seg * 4);
      tile[i][seg*4+0] = f2fp8(v.x * 64.f);
      tile[i][seg*4+1] = f2fp8(v.y * 64.f);
      tile[i][seg*4+2] = f2fp8(v.z * 64.f);
      tile[i][seg*4+3] = f2fp8(v.w * 64.f);
    }
    __syncthreads();
#pragma unroll
    for (int r = 0; r < 4; ++r) {
      int hi = ro + r * 16;
      unsigned a = tile[seg*4+0][hi];
      unsigned b = tile[seg*4+1][hi];
      unsigned c = tile[seg*4+2][hi];
      unsigned d = tile[seg*4+3][hi];
      *(unsigned*)(W1T + (size_t)(h0+hi)*KTOT + kp0 + seg*4) =
          a | (b << 8) | (c << 16) | (d << 24);
    }
  } else if (blk < 7840) {
    int id = (blk - 6272) * 256 + t;
    if (id >= 4 * 512 * 196) return;
    int pix = id % 196;
    int c   = (id / 196) & 511;
    int b   = id / (196 * 512);
    const float* p = feature + ((size_t)(b * 512 + c) * 8) * 196 + pix;
    float s = 0.f;
#pragma unroll
    for (int tt = 0; tt < 8; ++tt) s += p[tt * 196];
    fbhwc[((size_t)(b * 196 + pix)) * 512 + c] = s * 0.125f;
  } else {
    float* g = (float*)tile;
    int gid = (blk - 7840) * 256 + t;
    int b = gid >> 9;
    if (t < 128) g[t] = gtb[b * 128 + t];
    __syncthreads();
    float x1 = prop[gid * 4 + 0], y1 = prop[gid * 4 + 1];
    float x2 = prop[gid * 4 + 2], y2 = prop[gid * 4 + 3];
    float aa = (x2 - x1) * (y2 - y1);
    float best = -1e30f; int arg = 0;
    for (int m = 0; m < 32; ++m) {
      float gx1 = g[m*4], gy1 = g[m*4+1], gx2 = g[m*4+2], gy2 = g[m*4+3];
      float iw = fmaxf(fminf(x2, gx2) - fmaxf(x1, gx1), 0.f);
      float ih = fmaxf(fminf(y2, gy2) - fmaxf(y1, gy1), 0.f);
      float inter = iw * ih;
      float ab = (gx2 - gx1) * (gy2 - gy1);
      float iou = inter / (aa + ab - inter + 1e-8f);
      if (iou > best) { best = iou; arg = m; }
    }
    max_iou[gid] = best; assign[gid] = arg;
    if (best >= 0.85f) atomicOr(flag, 1);
  }
}

// ---- k_pre2: ROI-pool -> fp8 Apool, 4 blocks/box (bins 0-11/12-23/24-35/36-48)
__global__ __launch_bounds__(256) void k_pre2(
    const float* __restrict__ fbhwc, const float* __restrict__ prop,
    const void* ihp, const void* iwp, unsigned char* __restrict__ Apool) {
  int blk = blockIdx.x;
  int t = threadIdx.x;
  int n = blk >> 2;
  int q = blk & 3;
  int start = q * 12;
  int end   = (q == 3) ? 49 : start + 12;
  float sy = 14.f / scalar_f(ihp);
  float sx = 14.f / scalar_f(iwp);
  float bx1 = prop[n*4+0]*sx, by1 = prop[n*4+1]*sy;
  float bx2 = prop[n*4+2]*sx, by2 = prop[n*4+3]*sy;
  const float* fb = fbhwc + (size_t)(n >> 9) * 196 * 512;
  unsigned char* arow = Apool + (size_t)n * KTOT;
  int c4 = (t & 127) << 2;
  int bh = t >> 7;
  for (int b2i = start; b2i < end; b2i += 2) {
    int bin = b2i + bh;
    if (bin >= end) continue;
    int py = bin / 7, px = bin - py * 7;
    float y = by1 + ((py + 0.5f) * (1.f/7.f)) * (by2 - by1) - 0.5f;
    float x = bx1 + ((px + 0.5f) * (1.f/7.f)) * (bx2 - bx1) - 0.5f;
    float y0f = floorf(y), x0f = floorf(x);
    float wy = y - y0f, wx = x - x0f;
    int y0  = min(max((int)y0f, 0), 13);
    int y1i = min(max((int)y0f + 1, 0), 13);
    int x0  = min(max((int)x0f, 0), 13);
    int x1i = min(max((int)x0f + 1, 0), 13);
    float w00 = (1.f - wy) * (1.f - wx), w01 = (1.f - wy) * wx;
    float w10 = wy * (1.f - wx),         w11 = wy * wx;
    const float4 f00 = *(const float4*)(fb + (y0 * 14 + x0 ) * 512 + c4);
    const float4 f01 = *(const float4*)(fb + (y0 * 14 + x1i) * 512 + c4);
    const float4 f10 = *(const float4*)(fb + (y1i * 14 + x0 ) * 512 + c4);
    const float4 f11 = *(const float4*)(fb + (y1i * 14 + x1i) * 512 + c4);
    float vx = f00.x*w00 + f01.x*w01 + f10.x*w10 + f11.x*w11;
    float vy = f00.y*w00 + f01.y*w01 + f10.y*w10 + f11.y*w11;
    float vz = f00.z*w00 + f01.z*w01 + f10.z*w10 + f11.z*w11;
    float vw = f00.w*w00 + f01.w*w01 + f10.w*w10 + f11.w*w11;
    unsigned pk = (unsigned)f2fp8(vx) | ((unsigned)f2fp8(vy) << 8)
                | ((unsigned)f2fp8(vz) << 16) | ((unsigned)f2fp8(vw) << 24);
    *(unsigned*)(arow + bin * 512 + c4) = pk;
  }
}

__device__ __forceinline__ void gload16(const unsigned char* g, unsigned char* l) {
  __builtin_amdgcn_global_load_lds(
      (const __attribute__((address_space(1))) unsigned int*)g,
      (__attribute__((address_space(3))) unsigned int*)l, 16, 0, 0);
}

// ---- GEMM1 fp8 (round-15 kernel verbatim — best measured 88.5 us):
//      256x256 tile, BK=64, ring-4 lead-2 vmcnt(4), setprio around MFMA,
//      rolling in-place register refill. Grid = 256 blocks = 1/CU. 128KB LDS.
__global__ __launch_bounds__(512, 2) void k_gemm1(
    const unsigned char* __restrict__ A,   // 2048 x 25088 fp8
    const unsigned char* __restrict__ B,   // 1024 x 25088 fp8
    unsigned short* __restrict__ hp)       // 8 x 2048 x 1024 bf16 partials (x64 scale)
{
  extern __shared__ unsigned char lds[];   // 4 slots x 32768 B: [A 16K | B 16K]
  const int tid  = threadIdx.x;
  const int w    = tid >> 6;
  const int lane = tid & 63;
  const int l15  = lane & 15;
  const int wr = w >> 2, wc = w & 3;
  const int bid = (int)blockIdx.x;
  const int wg  = (bid & 7) * 32 + (bid >> 3);
  const int kb  = wg >> 5;
  const int gy  = (wg >> 2) & 7;
  const int gx  = wg & 3;

  f32x4 acc[8][4];
  const f32x4 zero = {0.f, 0.f, 0.f, 0.f};
#pragma unroll
  for (int m = 0; m < 8; ++m)
#pragma unroll
    for (int n = 0; n < 4; ++n) acc[m][n] = zero;

  const int xsw  = (tid & 7) ^ ((tid >> 3) & 7);
  const int rloc = ((tid >> 3) << 1) + (xsw >> 2);
  const int qsrc = xsw & 3;
  const size_t kbase = (size_t)kb * 3136;
  const unsigned char* gAp = A + (size_t)(gy * 256 + rloc) * KTOT + kbase + qsrc * 16;
  const unsigned char* gBp = B + (size_t)(gx * 256 + rloc) * KTOT + kbase + qsrc * 16;
  const int dstc = tid * 16;

  const int g4   = lane >> 4;
  const int qb   = g4 >> 1;
  const int h8   = (g4 & 1) * 8;
  const int rpar = (l15 & 1) << 2;
  const int lin  = l15 >> 1;
  const int P0 = ((qb)     | rpar) ^ lin;
  const int P1 = ((qb + 2) | rpar) ^ lin;
  const int aoff0 = wr * 8192 + lin * 128 + P0 * 16 + h8;
  const int aoff1 = wr * 8192 + lin * 128 + P1 * 16 + h8;
  const int boff0 = 16384 + wc * 4096 + lin * 128 + P0 * 16 + h8;
  const int boff1 = 16384 + wc * 4096 + lin * 128 + P1 * 16 + h8;

  long A0[8], A1[8], Bk0[4], Bk1[4];

#define STG(SLOT, KN) { \
    gload16(gAp + (KN),                      lds + (SLOT)*32768 + dstc); \
    gload16(gAp + (KN) + (size_t)128 * KTOT, lds + (SLOT)*32768 + 8192 + dstc); \
    gload16(gBp + (KN),                      lds + (SLOT)*32768 + 16384 + dstc); \
    gload16(gBp + (KN) + (size_t)128 * KTOT, lds + (SLOT)*32768 + 24576 + dstc); }
#define LDA(m, SLOT) { \
    A0[m] = *(const long*)(lds + (SLOT)*32768 + aoff0 + (m)*1024); \
    A1[m] = *(const long*)(lds + (SLOT)*32768 + aoff1 + (m)*1024); }
#define LDB(n, SLOT) { \
    Bk0[n] = *(const long*)(lds + (SLOT)*32768 + boff0 + (n)*1024); \
    Bk1[n] = *(const long*)(lds + (SLOT)*32768 + boff1 + (n)*1024); }
#define VM4 asm volatile("s_waitcnt vmcnt(4)" ::: "memory");
#define VM0 asm volatile("s_waitcnt vmcnt(0)" ::: "memory");
#define VMN

#define STEP(CS, DOSTG, KN, VMASM, DOREFILL)                                   \
  {                                                                            \
    if (DOSTG) STG((((CS)+2)&3), KN)                                           \
    VMASM                                                                      \
    __builtin_amdgcn_s_barrier();                                              \
    __builtin_amdgcn_s_setprio(1);                                             \
    _Pragma("unroll") for (int m = 0; m < 8; ++m) {                            \
      _Pragma("unroll") for (int n = 0; n < 4; ++n) {                          \
        acc[m][n] = __builtin_amdgcn_mfma_f32_16x16x32_fp8_fp8(                \
            A0[m], Bk0[n], acc[m][n], 0, 0, 0);                                \
        acc[m][n] = __builtin_amdgcn_mfma_f32_16x16x32_fp8_fp8(                \
            A1[m], Bk1[n], acc[m][n], 0, 0, 0);                                \
      }                                                                        \
      if (DOREFILL) LDA(m, (((CS)+1)&3))                                       \
    }                                                                          \
    if (DOREFILL) { _Pragma("unroll") for (int n = 0; n < 4; ++n)              \
                      LDB(n, (((CS)+1)&3)) }                                   \
    __builtin_amdgcn_s_setprio(0);                                             \
  }

  // prologue: stage slots 0,1 (k=0,64); vmcnt(4) -> slot0 landed.
  STG(0, 0)
  STG(1, 64)
  VM4
  __builtin_amdgcn_s_barrier();
#pragma unroll
  for (int m = 0; m < 8; ++m) LDA(m, 0)
#pragma unroll
  for (int n = 0; n < 4; ++n) LDB(n, 0)

  // main: 49 steps. 0..43 quads (stage s+2 <= 45); tail 44,45,46 stage
  // 46,47,48; 47 drains, 48 computes last.
#pragma unroll 1
  for (int s4 = 0; s4 < 44; s4 += 4) {
    STEP(0, true, (size_t)(s4 + 2) * 64, VM4, true)
    STEP(1, true, (size_t)(s4 + 3) * 64, VM4, true)
    STEP(2, true, (size_t)(s4 + 4) * 64, VM4, true)
    STEP(3, true, (size_t)(s4 + 5) * 64, VM4, true)
  }
  STEP(0, true, (size_t)46 * 64, VM4, true)   // step 44
  STEP(1, true, (size_t)47 * 64, VM4, true)   // step 45
  STEP(2, true, (size_t)48 * 64, VM4, true)   // step 46
  STEP(3, false, 0, VM0, true)                // step 47 (drain; slot0 ready)
  STEP(0, false, 0, VMN, false)               // step 48

#undef STEP
#undef VMN
#undef VM0
#undef VM4
#undef LDB
#undef LDA
#undef STG

  unsigned short* o = hp + (size_t)kb * (2048u * 1024u);
  const int r0 = gy * 256 + wr * 128 + ((lane >> 4) << 2);
  const int c0 = gx * 256 + wc * 64 + l15;
#pragma unroll
  for (int m = 0; m < 8; ++m)
#pragma unroll
    for (int n = 0; n < 4; ++n)
#pragma unroll
      for (int j = 0; j < 4; ++j)
        o[(size_t)(r0 + m * 16 + j) * 1024 + c0 + n * 16] = f2bf(acc[m][n][j]);
}

// ---- GEMM template (GEMM2 only, bf16): 128x128 tile, 2-phase dbuf
__device__ __forceinline__ void gload16s(const unsigned short* g, unsigned short* l) {
  __builtin_amdgcn_global_load_lds(
      (const __attribute__((address_space(1))) unsigned int*)g,
      (__attribute__((address_space(3))) unsigned int*)l, 16, 0, 0);
}

template<int OUTBF>
__global__ __launch_bounds__(256, 4) void k_gemm(
    const unsigned short* __restrict__ A,
    const unsigned short* __restrict__ B,
    void* __restrict__ outp,
    int Kst, int kIters, int nTileBits, int mTileBits, int ldc)
{
  __shared__ unsigned short As[2][4096];
  __shared__ unsigned short Bs[2][4096];
  const int tid  = threadIdx.x;
  const int w    = tid >> 6;
  const int lane = tid & 63;
  const int nwg = (int)gridDim.x, cpx = nwg >> 3;
  const int bid = (int)blockIdx.x;
  const int wg  = (bid & 7) * cpx + (bid >> 3);
  const int kb  = wg >> (mTileBits + nTileBits);
  const int rem = wg & ((1 << (mTileBits + nTileBits)) - 1);
  const int gy  = rem >> nTileBits;
  const int gx  = rem & ((1 << nTileBits) - 1);
  const int wr = w >> 1, wc = w & 1;

  f32x4 acc[4][4];
  const f32x4 zero = {0.f, 0.f, 0.f, 0.f};
#pragma unroll
  for (int m = 0; m < 4; ++m)
#pragma unroll
    for (int n = 0; n < 4; ++n) acc[m][n] = zero;

  const int r0   = 32 * w + (lane >> 2);
  const int qsrc = (lane & 3) ^ ((lane >> 3) & 3);
  const size_t kbase = (size_t)kb * kIters * 32;
  const unsigned short* gA = A + (size_t)(gy * 128 + r0) * Kst + kbase + qsrc * 8;
  const unsigned short* gB = B + (size_t)(gx * 128 + r0) * Kst + kbase + qsrc * 8;
  const int ldst = r0 * 32 + (lane & 3) * 8;

  const int swq = ((lane >> 4) ^ ((lane >> 1) & 3)) * 8;
  const int ar = (wr * 64 + (lane & 15)) * 32 + swq;
  const int br = (wc * 64 + (lane & 15)) * 32 + swq;

#define STAGE(bufi, it) do {                                         \
    const unsigned short* pa = gA + (size_t)(it) * 32;               \
    const unsigned short* pb = gB + (size_t)(it) * 32;               \
    gload16s(pa,                      &As[bufi][ldst]);              \
    gload16s(pa + (size_t)16 * Kst,   &As[bufi][ldst + 512]);        \
    gload16s(pb,                      &Bs[bufi][ldst]);              \
    gload16s(pb + (size_t)16 * Kst,   &Bs[bufi][ldst + 512]);        \
  } while (0)

  STAGE(0, 0);
  int cur = 0;
  for (int kk = 0; kk < kIters; ++kk) {
    __syncthreads();
    if (kk + 1 < kIters) STAGE(cur ^ 1, kk + 1);
    bf16x8 af[4], bfr[4];
#pragma unroll
    for (int m = 0; m < 4; ++m)
      af[m] = *reinterpret_cast<const bf16x8*>(&As[cur][ar + m * 512]);
#pragma unroll
    for (int n = 0; n < 4; ++n)
      bfr[n] = *reinterpret_cast<const bf16x8*>(&Bs[cur][br + n * 512]);
#pragma unroll
    for (int m = 0; m < 4; ++m)
#pragma unroll
      for (int n = 0; n < 4; ++n)
        acc[m][n] = __builtin_amdgcn_mfma_f32_16x16x32_bf16(af[m], bfr[n], acc[m][n], 0, 0, 0);
    cur ^= 1;
  }
#undef STAGE

  const size_t M = (size_t)(1 << mTileBits) * 128;
  const size_t splitStride = M * (size_t)ldc;
  const int r0o = gy * 128 + wr * 64 + ((lane >> 4) << 2);
  const int c0o = gx * 128 + wc * 64 + (lane & 15);
  if (OUTBF) {
    unsigned short* o = (unsigned short*)outp + (size_t)kb * splitStride;
#pragma unroll
    for (int m = 0; m < 4; ++m)
#pragma unroll
      for (int n = 0; n < 4; ++n)
#pragma unroll
        for (int j = 0; j < 4; ++j)
          o[(size_t)(r0o + m * 16 + j) * ldc + c0o + n * 16] = f2bf(acc[m][n][j]);
  } else {
    float* o = (float*)outp + (size_t)kb * splitStride;
#pragma unroll
    for (int m = 0; m < 4; ++m)
#pragma unroll
      for (int n = 0; n < 4; ++n)
#pragma unroll
        for (int j = 0; j < 4; ++j)
          o[(size_t)(r0o + m * 16 + j) * ldc + c0o + n * 16] = acc[m][n][j];
  }
}

// ---- combine (x 1/64 un-scale) + bias + ReLU -> hidden bf16; + W2 transpose
__global__ __launch_bounds__(256) void k_combine(const unsigned short* __restrict__ hp,
                                                 const float* __restrict__ b1,
                                                 unsigned short* __restrict__ hidden,
                                                 const float* __restrict__ W2,
                                                 unsigned short* __restrict__ W2T) {
  int blk = blockIdx.x;
  if (blk >= 1024) {
    int id = (blk - 1024) * 256 + threadIdx.x;
    int cls = id >> 10, k = id & 1023;
    float v = (cls < 80) ? W2[(size_t)k * 80 + cls] : 0.f;
    W2T[id] = f2bf(v);
    return;
  }
  int gid = blk * 256 + threadIdx.x;
  int id8 = gid * 8;
  int h = id8 & 1023;
  float a[8] = {0.f, 0.f, 0.f, 0.f, 0.f, 0.f, 0.f, 0.f};
#pragma unroll
  for (int s = 0; s < 8; ++s) {
    uint4 u = *(const uint4*)(hp + (size_t)s * 2097152 + id8);
    unsigned uu[4] = {u.x, u.y, u.z, u.w};
#pragma unroll
    for (int q = 0; q < 4; ++q) {
      union { unsigned u; float f; } lo, hi;
      lo.u = uu[q] << 16; hi.u = uu[q] & 0xFFFF0000u;
      a[2*q]   += lo.f;
      a[2*q+1] += hi.f;
    }
  }
  unsigned out[4];
#pragma unroll
  for (int q = 0; q < 4; ++q) {
    float v0 = a[2*q]   * 0.015625f + b1[h + 2*q];
    float v1 = a[2*q+1] * 0.015625f + b1[h + 2*q + 1];
    unsigned l  = f2bf(fmaxf(v0, 0.f));
    unsigned hh = f2bf(fmaxf(v1, 0.f));
    out[q] = l | (hh << 16);
  }
  *(uint4*)(hidden + id8) = make_uint4(out[0], out[1], out[2], out[3]);
}

// ---- BCE from gemm2 split-K partials (8 x 2048 x 128 f32)
__global__ __launch_bounds__(256) void k_bce(const float* __restrict__ hp2,
                                             const float* __restrict__ b2,
                                             const float* __restrict__ gtc,
                                             const int* __restrict__ assign,
                                             float* __restrict__ per) {
  __shared__ float red[256];
  int t = threadIdx.x;
  int box = t >> 4, li = t & 15;
  int n = blockIdx.x * 16 + box;
  int lab = ((n >> 9) * 32 + assign[n]) * 80;
  float s = 0.f;
#pragma unroll
  for (int j = 0; j < 5; ++j) {
    int c = li + 16 * j;
    size_t o = (size_t)n * 128 + c;
    float x = b2[c];
#pragma unroll
    for (int sp = 0; sp < 8; ++sp) x += hp2[o + (size_t)sp * 262144];
    float y = gtc[lab + c];
    float ce = log1pf(expf(-fabsf(x)));
    s += y * (fmaxf(-x, 0.f) + ce) + (1.f - y) * (fmaxf(x, 0.f) + ce);
  }
  red[t] = s;
  __syncthreads();
  if (li == 0) {
    float tot = 0.f;
#pragma unroll
    for (int i = 0; i < 16; ++i) tot += red[box * 16 + i];
    per[n] = tot * (1.f / 80.f);
  }
}

// ---- fg-masked per-batch mean
__global__ __launch_bounds__(512) void k_reduce(const float* __restrict__ per,
                                                const float* __restrict__ max_iou,
                                                const int* __restrict__ flag,
                                                float* __restrict__ out) {
  __shared__ float sv[8], sf[8];
  int b = blockIdx.x, tid = threadIdx.x;
  float thr = (*flag) ? 0.85f : 0.5f;
  int n = b * 512 + tid;
  float f = (max_iou[n] >= thr) ? 1.f : 0.f;
  float v = per[n] * f;
#pragma unroll
  for (int o = 32; o > 0; o >>= 1) {
    v += __shfl_down(v, o);
    f += __shfl_down(f, o);
  }
  int wv = tid >> 6;
  if ((tid & 63) == 0) { sv[wv] = v; sf[wv] = f; }
  __syncthreads();
  if (tid == 0) {
    float S = 0.f, F = 0.f;
#pragma unroll
    for (int i = 0; i < 8; ++i) { S += sv[i]; F += sf[i]; }
    out[b] = (F > 0.f) ? S / fmaxf(F, 1.f) : 0.f;
  }
}

extern "C" void kernel_launch(void* const* d_in, const int* in_sizes, int n_in,
                              void* d_out, int out_size, void* d_ws, size_t ws_size,
                              hipStream_t stream) {
  const float* feature = (const float*)d_in[0];
  const float* prop    = (const float*)d_in[1];
  const float* gtb     = (const float*)d_in[2];
  const float* gtc     = (const float*)d_in[3];
  const float* W1      = (const float*)d_in[4];
  const float* b1      = (const float*)d_in[5];
  const float* W2      = (const float*)d_in[6];
  const float* b2      = (const float*)d_in[7];
  const void*  ihp     = d_in[8];
  const void*  iwp     = d_in[9];

  char* ws = (char*)d_ws;
  float*          fbhwc  = (float*)(ws);
  unsigned char*  W1T    = (unsigned char*)(ws + 1605632);
  unsigned char*  Apool  = (unsigned char*)(ws + 52985856);
  unsigned short* hp     = (unsigned short*)(ws + 155746304);
  float*          max_iou= (float*)(ws + 189300736);
  int*            assign = (int*)(ws + 189308928);
  float*          per    = (float*)(ws + 189317120);
  int*            flag   = (int*)(ws + 189325312);
  unsigned short* hidden = (unsigned short*)W1T;
  unsigned short* W2T    = (unsigned short*)Apool;
  float*          hp2    = (float*)((char*)Apool + 262144);

  hipFuncSetAttribute((const void*)k_gemm1,
                      hipFuncAttributeMaxDynamicSharedMemorySize, 131072);

  hipMemsetAsync(flag, 0, sizeof(int), stream);
  k_pre1   <<<7848, 256, 0, stream>>>(W1, W1T, feature, fbhwc, prop, gtb,
                                      max_iou, assign, flag);
  k_pre2   <<<8192, 256, 0, stream>>>(fbhwc, prop, ihp, iwp, Apool);
  k_gemm1  <<<256, 512, 131072, stream>>>(Apool, W1T, hp);
  k_combine<<<1536, 256, 0, stream>>>(hp, b1, hidden, W2, W2T);
  k_gemm<0><<<128, 256, 0, stream>>>(hidden, W2T, hp2, 1024, 4, 0, 4, 128);
  k_bce    <<<128, 256, 0, stream>>>(hp2, b2, gtc, assign, per);
  k_reduce <<<4, 512, 0, stream>>>(per, max_iou, flag, (float*)d_out);
}